// Round 11
// baseline (185.448 us; speedup 1.0000x reference)
//
#include <hip/hip_runtime.h>
#include <float.h>

// Problem constants (fixed by the reference): B=2, N=M=8192, G=256
#define B_ 2
#define N_ 8192
#define G_ 256
// CELL = abs(2*(-35)/256) = 70/256 = 0.2734375 exactly representable in fp32
constexpr float X_MIN_F = -35.0f;
constexpr float CELL_F  = 0.2734375f;

// Spatial hash for exact 1-NN: 16^3 cells over [-35,35], cell = 4.375.
// Expected L1-NN radius ~3.1 < 4.3 ring-bound -> ring scan beyond the 3x3x3
// box is almost never taken.
#define GC   16
#define GS   4.375f
#define CAP  32            // slots/cell; lambda=2 => P(>32) ~ 1e-25; overflow
                           // list guarantees exactness regardless.

using u64 = unsigned long long;

// Workspace layout (bytes):
//   grid   i32[B*G*G]        [0,      524288)   packed (n<<1)|label, -1 inval
//   accum  16B               [524288, 524304)   {f32 sum,i32 cnt,u32 tkt,pad}
//   chamx  u64[B*N]          [524352, 655424)   packed (distbits<<32)|idx
//   chamy  u32[B*N]          [655424, 720960)   dist bits (y-dir, no argmin)
//   cnt    i32[4][4096]      [720960, 786496)   per-cell counts (memset 0)
//   ocnt   i32[4]            [786496, 786560)   overflow counts (memset 0)
//   cells  f4[4][4096][32]   [786560, 9175168)  {x,y,z,idx-bits}
//   oflow  f4[4][8192]       [9175168,9699456)  overflow records
#define OFF_ACCUM 524288
#define OFF_CHAMX 524352
#define OFF_CHAMY 655424
#define OFF_CNT   720960
#define OFF_OCNT  786496
#define OFF_CELLS 786560
#define OFF_OFLOW 9175168

__device__ __forceinline__ int cell_of(float x) {
    int c = (int)((x + 35.0f) * (1.0f / GS));
    return c < 0 ? 0 : (c > 15 ? 15 : c);
}

// ---------------------------------------------------------------------------
// Binning: 32768 points (grid g = b*2 + set; set0 = p_j targets, set1 = p_i
// targets). Also folds in grid=-1 init and accum zeroing (consumed only after
// this kernel's boundary). cnt/ocnt pre-zeroed by hipMemsetAsync.
// ---------------------------------------------------------------------------
__global__ __launch_bounds__(256) void bin_kernel(
    const float* __restrict__ p_i, const float* __restrict__ p_j,
    int* __restrict__ cnt, int* __restrict__ ocnt,
    float4* __restrict__ cells, float4* __restrict__ oflow,
    int* __restrict__ grid, unsigned* __restrict__ accum)
{
    const int pi = blockIdx.x * 256 + threadIdx.x;   // [0, 32768)

    // folded init: grid = -1 (32768 uint4 = 512 KB), accum = 0
    ((uint4*)grid)[pi] = make_uint4(~0u, ~0u, ~0u, ~0u);
    if (pi < 4) accum[pi] = 0u;

    const int set = pi >> 14;                        // 0: p_j, 1: p_i
    const int b   = (pi >> 13) & 1;
    const int n   = pi & (N_ - 1);
    const float* src = set ? p_i : p_j;
    const float* pp  = src + ((size_t)b * N_ + n) * 3;
    float x = pp[0], y = pp[1], z = pp[2];
    const int g = b * 2 + set;
    const int cell = (cell_of(x) << 8) | (cell_of(y) << 4) | cell_of(z);

    float4 rec = make_float4(x, y, z, __uint_as_float((unsigned)n));
    int slot = atomicAdd(&cnt[(g << 12) | cell], 1);
    if (slot < CAP)
        cells[(((size_t)(g << 12) | cell) << 5) + slot] = rec;
    else {
        int o = atomicAdd(&ocnt[g], 1);
        oflow[((size_t)g << 13) + o] = rec;
    }
}

// ---------------------------------------------------------------------------
// Exact 1-NN via spatial hash. 32768 queries x 4 roles = 512 blocks x 256.
//   Inner 3x3x3 box split across 4 roles (linear cell idx % 4), combined via
//   LDS u64 atomicMin on packed (distbits<<32)|idx.
//   Role 0: ring expansion r=2.. while (r-1)*4.3 <= best (conservative: true
//   distance to a ring-r point >= (r-1)*4.375 - fp-binning eps, and the 0.075/
//   ring slack dominates eps -> no true NN or exact tie is ever pruned), then
//   unconditional overflow scan, then write result.
// Exactness: identical left-assoc L1 expression as reference; u64-min over a
// candidate superset containing all points with d == min => min dist, then
// min idx = numpy first-occurrence argmin.
// ---------------------------------------------------------------------------
__global__ __launch_bounds__(256) void nn_grid_kernel(
    const float* __restrict__ p_i, const float* __restrict__ p_j,
    const int* __restrict__ cnt, const int* __restrict__ ocnt,
    const float4* __restrict__ cells, const float4* __restrict__ oflow,
    u64* __restrict__ chamx, unsigned* __restrict__ chamy)
{
    __shared__ u64 sb[64];
    const int tid  = threadIdx.x;
    const int ql   = tid >> 2;                       // query within block
    const int role = tid & 3;
    const int qg   = blockIdx.x * 64 + ql;           // [0, 32768)
    const int dir  = qg >> 14;                       // 0: p_i->p_j, 1: p_j->p_i
    const int b    = (qg >> 13) & 1;
    const int n    = qg & (N_ - 1);

    const float* Qp = dir ? p_j : p_i;
    const float* qp = Qp + ((size_t)b * N_ + n) * 3;
    const float qx = qp[0], qy = qp[1], qz = qp[2];
    const int g  = b * 2 + dir;                      // target grid
    const int cx = cell_of(qx), cy = cell_of(qy), cz = cell_of(qz);

    if (tid < 64) sb[tid] = ~0ull;
    __syncthreads();

    u64 best = ~0ull;
    // inner 3x3x3 box, cells distributed across roles
    {
        int l = 0;
        for (int dx = -1; dx <= 1; dx++)
            for (int dy = -1; dy <= 1; dy++)
                for (int dz = -1; dz <= 1; dz++, l++) {
                    if ((l & 3) != role) continue;
                    int ax = cx + dx, ay = cy + dy, az = cz + dz;
                    if ((unsigned)ax > 15u || (unsigned)ay > 15u ||
                        (unsigned)az > 15u) continue;
                    int cell = (ax << 8) | (ay << 4) | az;
                    int c = cnt[(g << 12) | cell];
                    c = c > CAP ? CAP : c;
                    const float4* base =
                        cells + (((size_t)(g << 12) | cell) << 5);
                    for (int k = 0; k < c; k++) {
                        float4 pt = base[k];
                        // bit-match ref: (|d0| + |d1|) + |d2|, left-assoc fp32
                        float d = (fabsf(qx - pt.x) + fabsf(qy - pt.y))
                                  + fabsf(qz - pt.z);
                        u64 pk = ((u64)__float_as_uint(d) << 32)
                                 | (unsigned)__float_as_uint(pt.w);
                        best = pk < best ? pk : best;
                    }
                }
    }
    atomicMin(&sb[ql], best);
    __syncthreads();

    if (role == 0) {
        best = sb[ql];

        // outer rings (rarely taken: typical NN dist ~3.1 < 4.3)
        for (int r = 2; r <= 15; r++) {
            unsigned db = (unsigned)(best >> 32);
            float bd = (db == 0xFFFFFFFFu) ? FLT_MAX : __uint_as_float(db);
            if ((float)(r - 1) * 4.3f > bd) break;
            for (int dx = -r; dx <= r; dx++)
                for (int dy = -r; dy <= r; dy++)
                    for (int dz = -r; dz <= r; dz++) {
                        int mx = dx < 0 ? -dx : dx;
                        int my = dy < 0 ? -dy : dy;
                        int mz = dz < 0 ? -dz : dz;
                        int m = mx > my ? mx : my;
                        m = m > mz ? m : mz;
                        if (m != r) continue;
                        int ax = cx + dx, ay = cy + dy, az = cz + dz;
                        if ((unsigned)ax > 15u || (unsigned)ay > 15u ||
                            (unsigned)az > 15u) continue;
                        int cell = (ax << 8) | (ay << 4) | az;
                        int c = cnt[(g << 12) | cell];
                        c = c > CAP ? CAP : c;
                        const float4* base =
                            cells + (((size_t)(g << 12) | cell) << 5);
                        for (int k = 0; k < c; k++) {
                            float4 pt = base[k];
                            float d = (fabsf(qx - pt.x) + fabsf(qy - pt.y))
                                      + fabsf(qz - pt.z);
                            u64 pk = ((u64)__float_as_uint(d) << 32)
                                     | (unsigned)__float_as_uint(pt.w);
                            best = pk < best ? pk : best;
                        }
                    }
        }

        // overflow list: scanned unconditionally (normally empty)
        int oc = ocnt[g];
        for (int k = 0; k < oc; k++) {
            float4 pt = oflow[((size_t)g << 13) + k];
            float d = (fabsf(qx - pt.x) + fabsf(qy - pt.y))
                      + fabsf(qz - pt.z);
            u64 pk = ((u64)__float_as_uint(d) << 32)
                     | (unsigned)__float_as_uint(pt.w);
            best = pk < best ? pk : best;
        }

        if (dir == 0) chamx[(size_t)b * N_ + n] = best;
        else          chamy[(size_t)b * N_ + n] = (unsigned)(best >> 32);
    }
}

// ---------------------------------------------------------------------------
// Per-point label + scatter into the (B,G,G) grid (proven R8 kernel).
// Last-write-wins in point order n == max n wins -> atomicMax on packed
// (n<<1 | label); grid initialized to -1 by bin_kernel.
// ---------------------------------------------------------------------------
__global__ __launch_bounds__(256) void scatter_kernel(
    const u64* __restrict__ chamx, const unsigned* __restrict__ chamy,
    const float* __restrict__ flow, const int* __restrict__ nflow,
    const float* __restrict__ Pj, int* __restrict__ grid)
{
    int i = blockIdx.x * 256 + threadIdx.x;      // i in [0, B*N)
    int b = i >> 13;                             // N = 8192
    int n = i & (N_ - 1);

    u64 pX = chamx[i];
    float dx = __uint_as_float((unsigned)(pX >> 32));
    float dy = __uint_as_float(chamy[i]);
    float rigid = (dx + dy) * 0.5f;

    bool dyn  = flow[i] > rigid;
    int label = dyn ? 1 : 0;
    int idx   = dyn ? nflow[i] : (int)(unsigned)(pX & 0xFFFFFFFFull);

    const float* qp = Pj + ((size_t)b * N_ + idx) * 3;
    float x = qp[0], y = qp[1];

    // bit-match reference: (p - shift) / CELL, IEEE fp32 divide, trunc cast
    int cx = (int)((x - X_MIN_F) / CELL_F);
    int cy = (int)((y - X_MIN_F) / CELL_F);

    atomicMax(&grid[(b << 16) + cx * G_ + cy], (n << 1) | label);
}

// ---------------------------------------------------------------------------
// Cross-entropy over valid grid cells + fused finalize (proven R8 kernel).
// ---------------------------------------------------------------------------
__global__ __launch_bounds__(256) void ce_kernel(const float* __restrict__ mos,
                                                 const int* __restrict__ grid,
                                                 float* __restrict__ accum,
                                                 float* __restrict__ out)
{
    int i = blockIdx.x * 256 + threadIdx.x;      // i in [0, B*G*G) = 131072
    float lsum = 0.0f;
    int   lcnt = 0;

    int packed = grid[i];
    if (packed >= 0) {
        int b    = i >> 16;                      // G*G = 65536
        int cell = i & 0xFFFF;
        float m0 = mos[((size_t)b * 2 + 0) * 65536 + cell];
        float m1 = mos[((size_t)b * 2 + 1) * 65536 + cell];
        float mx = fmaxf(m0, m1);
        float lse = logf(expf(m0 - mx) + expf(m1 - mx));
        float sh  = ((packed & 1) ? m1 : m0) - mx;   // stable log_softmax
        lsum = sh - lse;
        lcnt = 1;
    }

    // wave-64 shuffle reduction
#pragma unroll
    for (int o = 32; o > 0; o >>= 1) {
        lsum += __shfl_down(lsum, o);
        lcnt += __shfl_down(lcnt, o);
    }
    __shared__ float wsum[4];
    __shared__ int   wcnt[4];
    int wave = threadIdx.x >> 6;
    if ((threadIdx.x & 63) == 0) { wsum[wave] = lsum; wcnt[wave] = lcnt; }
    __syncthreads();
    if (threadIdx.x == 0) {
        float s = wsum[0] + wsum[1] + wsum[2] + wsum[3];
        int   c = wcnt[0] + wcnt[1] + wcnt[2] + wcnt[3];
        atomicAdd(&accum[0], s);
        atomicAdd((int*)&accum[1], c);
        __threadfence();
        unsigned t = atomicAdd((unsigned*)&accum[2], 1u);
        if (t == gridDim.x - 1) {
            float S = atomicAdd(&accum[0], 0.0f);
            int   C = atomicAdd((int*)&accum[1], 0);
            out[0] = -S / (float)(C > 0 ? C : 1);
        }
    }
}

// ---------------------------------------------------------------------------
extern "C" void kernel_launch(void* const* d_in, const int* in_sizes, int n_in,
                              void* d_out, int out_size, void* d_ws, size_t ws_size,
                              hipStream_t stream)
{
    const float* p_i   = (const float*)d_in[0];   // (B,N,3)
    const float* mos   = (const float*)d_in[1];   // (B,2,G,G)
    const float* p_j   = (const float*)d_in[2];   // (B,M,3)
    const float* flow  = (const float*)d_in[3];   // (B,N)
    const int*   nflow = (const int*)d_in[4];     // (B,N,1)
    float* out = (float*)d_out;
    char* ws = (char*)d_ws;

    int*      grid  = (int*)ws;
    float*    accum = (float*)(ws + OFF_ACCUM);
    u64*      chamx = (u64*)(ws + OFF_CHAMX);
    unsigned* chamy = (unsigned*)(ws + OFF_CHAMY);
    int*      cnt   = (int*)(ws + OFF_CNT);
    int*      ocnt  = (int*)(ws + OFF_OCNT);
    float4*   cells = (float4*)(ws + OFF_CELLS);
    float4*   oflow = (float4*)(ws + OFF_OFLOW);

    // zero cell counters + overflow counters (64 KB + 64 B)
    hipMemsetAsync(ws + OFF_CNT, 0, OFF_CELLS - OFF_CNT, stream);

    bin_kernel<<<128, 256, 0, stream>>>(p_i, p_j, cnt, ocnt, cells, oflow,
                                        grid, (unsigned*)accum);
    nn_grid_kernel<<<512, 256, 0, stream>>>(p_i, p_j, cnt, ocnt, cells, oflow,
                                            chamx, chamy);
    scatter_kernel<<<(B_ * N_) / 256, 256, 0, stream>>>(chamx, chamy, flow,
                                                        nflow, p_j, grid);
    ce_kernel<<<(B_ * G_ * G_) / 256, 256, 0, stream>>>(mos, grid, accum, out);
}